// Round 2
// baseline (365.462 us; speedup 1.0000x reference)
//
#include <hip/hip_runtime.h>
#include <math.h>

#define NN 50000
#define NE 800000
#define NB 196        // dst buckets of 256 nodes: (NN+255)>>8

typedef float v4f __attribute__((ext_vector_type(4)));
typedef _Float16 v8h __attribute__((ext_vector_type(8)));

// ================= graph build: two-level bucket sort (dense writes) ==========

// Phase A: bucket histogram (bucket = dst>>8)
__global__ __launch_bounds__(256) void k_bhist(const int* __restrict__ dst,
                                               int* __restrict__ gbcnt) {
  __shared__ int lcnt[NB];
  int t = threadIdx.x;
  for (int i = t; i < NB; i += 256) lcnt[i] = 0;
  __syncthreads();
  int eb = blockIdx.x * 4096;
#pragma unroll
  for (int i = 0; i < 16; ++i) {
    int e = eb + i * 256 + t;
    if (e < NE) atomicAdd(&lcnt[dst[e] >> 8], 1);
  }
  __syncthreads();
  for (int i = t; i < NB; i += 256)
    if (lcnt[i]) atomicAdd(&gbcnt[i], lcnt[i]);
}

// Phase B: scan bucket counts -> boff[NB+1]; init cursors; offs[NN]=NE
__global__ __launch_bounds__(256) void k_bscan(const int* __restrict__ gbcnt,
                                               int* __restrict__ boff,
                                               int* __restrict__ gcur,
                                               int* __restrict__ offs) {
  __shared__ int sd[256];
  int t = threadIdx.x;
  int v = (t < NB) ? gbcnt[t] : 0;
  sd[t] = v;
  __syncthreads();
  for (int o = 1; o < 256; o <<= 1) {
    int u = (t >= o) ? sd[t - o] : 0;
    __syncthreads();
    sd[t] += u;
    __syncthreads();
  }
  if (t < NB) { int x = sd[t] - v; boff[t] = x; gcur[t] = x; }
  if (t == NB - 1) boff[NB] = sd[t];
  if (t == 0) offs[NN] = NE;
}

// Phase C: scatter packed edges into bucketed ebuf (per-block range reservation)
__global__ __launch_bounds__(256) void k_bscatter(const int* __restrict__ src,
                                                  const int* __restrict__ dst,
                                                  int* __restrict__ gcur,
                                                  unsigned* __restrict__ ebuf) {
  __shared__ int cnt[NB];
  __shared__ int base[NB];
  int t = threadIdx.x;
  for (int i = t; i < NB; i += 256) cnt[i] = 0;
  __syncthreads();
  int eb = blockIdx.x * 4096;
  unsigned pk[16];
  int bk[16], lp[16];
#pragma unroll
  for (int i = 0; i < 16; ++i) {
    int e = eb + i * 256 + t;
    if (e < NE) {
      int d = dst[e];
      int b = d >> 8;
      pk[i] = ((unsigned)src[e] << 8) | (unsigned)(d & 255);
      bk[i] = b;
      lp[i] = atomicAdd(&cnt[b], 1);
    }
  }
  __syncthreads();
  for (int i = t; i < NB; i += 256)
    base[i] = cnt[i] ? atomicAdd(&gcur[i], cnt[i]) : 0;
  __syncthreads();
#pragma unroll
  for (int i = 0; i < 16; ++i) {
    int e = eb + i * 256 + t;
    if (e < NE) ebuf[base[bk[i]] + lp[i]] = pk[i];
  }
}

// Phase D: per-bucket degree count + scan in LDS -> offs/invd; scatter src into
// a contiguous csr window (dense full-line writebacks).
__global__ __launch_bounds__(256) void k_bbuild(const unsigned* __restrict__ ebuf,
                                                const int* __restrict__ boff,
                                                int* __restrict__ offs,
                                                float* __restrict__ invd,
                                                int* __restrict__ csr) {
  __shared__ int dcnt[256];
  __shared__ int cur[256];
  int t = threadIdx.x;
  int b = blockIdx.x;
  int node0 = b << 8;
  int es = boff[b], ee = boff[b + 1];
  dcnt[t] = 0;
  __syncthreads();
  for (int e = es + t; e < ee; e += 256) atomicAdd(&dcnt[ebuf[e] & 255], 1);
  __syncthreads();
  int v = dcnt[t];
  cur[t] = v;
  __syncthreads();
  for (int o = 1; o < 256; o <<= 1) {
    int u = (t >= o) ? cur[t - o] : 0;
    __syncthreads();
    cur[t] += u;
    __syncthreads();
  }
  int excl = cur[t] - v;
  int node = node0 + t;
  if (node < NN) {
    offs[node] = es + excl;
    invd[node] = 1.0f / fmaxf((float)v, 1.0f);
  }
  __syncthreads();
  cur[t] = es + excl;
  __syncthreads();
  for (int e = es + t; e < ee; e += 256) {
    unsigned pk = ebuf[e];
    int p = atomicAdd(&cur[pk & 255], 1);
    csr[p] = (int)(pk >> 8);
  }
}

// ================= per-node mean aggregation (fp16 rows in+out) ===============
// feat: [n][64] fp16 -> one 128B burst per row; table is 6.4MB (L2-friendly).
// lane = slot*8 + cg; 16 rows in flight (8 slots x 2-deep).
// reduce: xor8/16/32 fold the 8 slots; lanes 0-7 write 8 fp16 means each.
__global__ __launch_bounds__(256) void k_aggregate(
    const _Float16* __restrict__ feat,
    const int* __restrict__ offs, const int* __restrict__ csr,
    const float* __restrict__ invd,
    _Float16* __restrict__ mean, int n) {
  int node = blockIdx.x * 4 + (threadIdx.x >> 6);
  int lane = threadIdx.x & 63;
  int slot = lane >> 3;     // 0..7 neighbor slot
  int cg   = lane & 7;      // 8 groups x 8 halfs = full 128B row
  if (node >= n) return;
  int s = offs[node], e = offs[node + 1];

  float a[8];
#pragma unroll
  for (int i = 0; i < 8; ++i) a[i] = 0.f;

  if (e > s) {
    int emax = e - 1;
    for (int p0 = s; p0 < e; p0 += 16) {
      int pa = p0 + slot, pb = p0 + 8 + slot;
      int ja = __builtin_nontemporal_load(csr + (pa < emax ? pa : emax));
      int jb = __builtin_nontemporal_load(csr + (pb < emax ? pb : emax));
      v8h va = *(const v8h*)(feat + (size_t)ja * 64 + cg * 8);
      v8h vb = *(const v8h*)(feat + (size_t)jb * 64 + cg * 8);
      if (pa < e) {
#pragma unroll
        for (int i = 0; i < 8; ++i) a[i] += (float)va[i];
      }
      if (pb < e) {
#pragma unroll
        for (int i = 0; i < 8; ++i) a[i] += (float)vb[i];
      }
    }
  }
#pragma unroll
  for (int i = 0; i < 8; ++i) {
    a[i] += __shfl_xor(a[i], 8, 64);   // fold slot bit0
    a[i] += __shfl_xor(a[i], 16, 64);  // slot bit1
    a[i] += __shfl_xor(a[i], 32, 64);  // slot bit2
  }
  if (lane < 8) {
    float d = invd[node];
    v8h o;
#pragma unroll
    for (int i = 0; i < 8; ++i) o[i] = (_Float16)(a[i] * d);
    *(v8h*)(mean + (size_t)node * 64 + lane * 8) = o;
  }
}

// ================= fused multi-source linear, MFMA fp16 =======================
// out = act( sum_s A_s @ (g_s W_s) + bias );
// A: fp16 rows (random-sign quantization washes out in colsum) -> 1 fragment.
// W: split-fp16 hi+lo (systematic error must stay tiny) -> 2 MFMAs/product.
// W^T staged in LDS (144B stride), double-buffered across sources.
struct LinArgs {
  const void*  a[6];       // fp32 ptr (isf32) or fp16 [n][64] row ptr
  const float* w[6];       // [64][64] fp32 blocks (row stride 64)
  int gidx[6];
  int stride[6];           // fp32 row stride
  int isf32[6];
  int nsrc;
  const float* bias;
  const float* skip;
  _Float16* outp;          // [n][64] fp16, or nullptr (colsum-only)
  float* colsum;           // [64] atomic target, or nullptr
  int n;
  int relu;
};

__global__ __launch_bounds__(256) void k_linear(LinArgs A) {
  __shared__ _Float16 sW[2][2][64 * 72];   // [buf][hi/lo][n*72+k]
  const int t    = threadIdx.x;
  const int lane = t & 63;
  const int wv   = t >> 6;
  const int qd   = lane >> 4;
  const int ln   = lane & 15;
  const int n0   = blockIdx.x * 64;

  v4f acc[4];
#pragma unroll
  for (int ct = 0; ct < 4; ++ct) acc[ct] = (v4f){0.f, 0.f, 0.f, 0.f};

  const int sn = t & 63;
  float wreg[16];
  auto loadW = [&](int s) {
    const float* w = A.w[s];
#pragma unroll
    for (int c = 0; c < 2; ++c) {
      int kb = (wv + 4 * c) * 8;
#pragma unroll
      for (int j = 0; j < 8; ++j)
        wreg[c * 8 + j] = w[(size_t)(kb + j) * 64 + sn];
    }
  };
  auto writeW = [&](int s, int b) {
    float gs = 1.0f;
    if (A.gidx[s] >= 0) gs = 1.0f / (1.0f + __expf(-A.skip[A.gidx[s]]));
#pragma unroll
    for (int c = 0; c < 2; ++c) {
      int cb = wv + 4 * c;
      v8h hv, lv;
#pragma unroll
      for (int j = 0; j < 8; ++j) {
        float f = wreg[c * 8 + j] * gs;
        _Float16 h = (_Float16)f;
        hv[j] = h;
        lv[j] = (_Float16)(f - (float)h);
      }
      *(v8h*)(&sW[b][0][sn * 72 + cb * 8]) = hv;
      *(v8h*)(&sW[b][1][sn * 72 + cb * 8]) = lv;
    }
  };

  const int arow = n0 + wv * 16 + ln;
  const bool arv = arow < A.n;
  v8h ah[2];
  auto loadA = [&](int s) {
    if (A.isf32[s]) {
      const float* a = (const float*)A.a[s];
      int st = A.stride[s];
#pragma unroll
      for (int ks = 0; ks < 2; ++ks) {
        v8h hv;
        if (arv) {
          const float* p = a + (size_t)arow * st + ks * 32 + qd * 8;
          float4 u0 = *(const float4*)(p);
          float4 u1 = *(const float4*)(p + 4);
          hv[0] = (_Float16)u0.x; hv[1] = (_Float16)u0.y;
          hv[2] = (_Float16)u0.z; hv[3] = (_Float16)u0.w;
          hv[4] = (_Float16)u1.x; hv[5] = (_Float16)u1.y;
          hv[6] = (_Float16)u1.z; hv[7] = (_Float16)u1.w;
        } else {
#pragma unroll
          for (int j = 0; j < 8; ++j) hv[j] = (_Float16)0.f;
        }
        ah[ks] = hv;
      }
    } else {
      const _Float16* ph = (const _Float16*)A.a[s] + (size_t)arow * 64;
      if (arv) {
#pragma unroll
        for (int ks = 0; ks < 2; ++ks)
          ah[ks] = *(const v8h*)(ph + ks * 32 + qd * 8);
      } else {
        v8h z;
#pragma unroll
        for (int j = 0; j < 8; ++j) z[j] = (_Float16)0.f;
        ah[0] = ah[1] = z;
      }
    }
  };

  loadW(0);
  writeW(0, 0);
  __syncthreads();

  for (int s = 0; s < A.nsrc; ++s) {
    loadA(s);
    if (s + 1 < A.nsrc) loadW(s + 1);
    const _Float16* wh = &sW[s & 1][0][0];
    const _Float16* wl = &sW[s & 1][1][0];
#pragma unroll
    for (int ks = 0; ks < 2; ++ks) {
#pragma unroll
      for (int ct = 0; ct < 4; ++ct) {
        int wn = ct * 16 + ln;
        v8h bh = *(const v8h*)(wh + wn * 72 + ks * 32 + qd * 8);
        v8h bl = *(const v8h*)(wl + wn * 72 + ks * 32 + qd * 8);
        acc[ct] = __builtin_amdgcn_mfma_f32_16x16x32_f16(ah[ks], bh, acc[ct], 0, 0, 0);
        acc[ct] = __builtin_amdgcn_mfma_f32_16x16x32_f16(ah[ks], bl, acc[ct], 0, 0, 0);
      }
    }
    if (s + 1 < A.nsrc) writeW(s + 1, (s + 1) & 1);
    __syncthreads();
  }

  float bvals[4];
#pragma unroll
  for (int ct = 0; ct < 4; ++ct) bvals[ct] = A.bias[ct * 16 + ln];

  float cs[4] = {0.f, 0.f, 0.f, 0.f};
#pragma unroll
  for (int ct = 0; ct < 4; ++ct) {
#pragma unroll
    for (int r = 0; r < 4; ++r) {
      int node = n0 + wv * 16 + qd * 4 + r;   // C/D: row=(lane>>4)*4+reg, col=lane&15
      float v = acc[ct][r] + bvals[ct];
      if (A.relu) v = fmaxf(v, 0.f);
      if (node < A.n) {
        if (A.outp) A.outp[(size_t)node * 64 + ct * 16 + ln] = (_Float16)v;
        cs[ct] += v;
      }
    }
  }
  if (A.colsum) {
    float* red = (float*)&sW[0][0][0];
#pragma unroll
    for (int ct = 0; ct < 4; ++ct) {
      float v = cs[ct];
      v += __shfl_xor(v, 16, 64);
      v += __shfl_xor(v, 32, 64);
      if (qd == 0) red[wv * 64 + ct * 16 + ln] = v;
    }
    __syncthreads();
    if (t < 64) {
      float ssum = red[t] + red[64 + t] + red[128 + t] + red[192 + t];
      atomicAdd(&A.colsum[t], ssum);
    }
  }
}

// ---------------- tiny post-MLP (single block) ----------------
__global__ __launch_bounds__(256) void k_post(const float* __restrict__ s,
                                              const float* __restrict__ w1, const float* __restrict__ b1,
                                              const float* __restrict__ w2, const float* __restrict__ b2,
                                              const float* __restrict__ w3, const float* __restrict__ b3,
                                              const float* __restrict__ w4, const float* __restrict__ b4,
                                              float* __restrict__ outp) {
  __shared__ float sh[256], h1[64], h2[64], h3[256];
  int t = threadIdx.x;
  sh[t] = s[t];
  __syncthreads();
  if (t < 64) {
    float a = b1[t];
    for (int k = 0; k < 256; ++k) a += sh[k] * w1[k * 64 + t];
    h1[t] = (a >= 0.f) ? a : 0.1f * a;   // leaky_relu 0.1
  }
  __syncthreads();
  if (t < 64) {
    float a = b2[t];
    for (int k = 0; k < 64; ++k) a += h1[k] * w2[k * 64 + t];
    h2[t] = fmaxf(a, 0.f);
  }
  __syncthreads();
  {
    float a = b3[t];
    for (int k = 0; k < 64; ++k) a += h2[k] * w3[k * 256 + t];
    h3[t] = fmaxf(a, 0.f);
  }
  __syncthreads();
  if (t < 64) {
    float a = b4[t];
    for (int k = 0; k < 256; ++k) a += h3[k] * w4[k * 64 + t];
    outp[t] = a;
  }
}

extern "C" void kernel_launch(void* const* d_in, const int* in_sizes, int n_in,
                              void* d_out, int out_size, void* d_ws, size_t ws_size,
                              hipStream_t stream) {
  const float* nf     = (const float*)d_in[0];
  const int*   ei     = (const int*)d_in[1];
  const float* pre_w1 = (const float*)d_in[2];
  const float* pre_b1 = (const float*)d_in[3];
  const float* pre_w2 = (const float*)d_in[4];
  const float* pre_b2 = (const float*)d_in[5];
  const float* skip   = (const float*)d_in[6];
  const float* wl0 = (const float*)d_in[7],  *bl0 = (const float*)d_in[8],  *wr0 = (const float*)d_in[9];
  const float* wl1 = (const float*)d_in[10], *bl1 = (const float*)d_in[11], *wr1 = (const float*)d_in[12];
  const float* wl2 = (const float*)d_in[13], *bl2 = (const float*)d_in[14], *wr2 = (const float*)d_in[15];
  const float* pw1 = (const float*)d_in[16], *pb1 = (const float*)d_in[17];
  const float* pw2 = (const float*)d_in[18], *pb2 = (const float*)d_in[19];
  const float* pw3 = (const float*)d_in[20], *pb3 = (const float*)d_in[21];
  const float* pw4 = (const float*)d_in[22], *pb4 = (const float*)d_in[23];
  float* out = (float*)d_out;

  const int N = NN, E = NE;

  // workspace carve-up
  char* ws = (char*)d_ws;
  size_t pos = 0;
  auto alloc = [&](size_t bytes) {
    char* p = ws + pos;
    pos += (bytes + 255) & ~(size_t)255;
    return (void*)p;
  };
  int*      gbcnt = (int*)alloc((size_t)NB * 4);
  int*      boff  = (int*)alloc((size_t)(NB + 1) * 4);
  int*      gcur  = (int*)alloc((size_t)NB * 4);
  unsigned* ebuf  = (unsigned*)alloc((size_t)E * 4);
  int*      offs  = (int*)alloc((size_t)(N + 1) * 4);
  float*    invd  = (float*)alloc((size_t)N * 4);
  int*      csr   = (int*)alloc((size_t)E * 4);
  const size_t PB = (size_t)N * 64 * 2;   // fp16 rows, bytes
  _Float16* t0 = (_Float16*)alloc(PB);
  _Float16* x  = (_Float16*)alloc(PB);
  _Float16* h0 = (_Float16*)alloc(PB);
  _Float16* h1 = (_Float16*)alloc(PB);
  _Float16* m0 = (_Float16*)alloc(PB);
  _Float16* m1 = (_Float16*)alloc(PB);
  _Float16* m2 = (_Float16*)alloc(PB);
  float* sv = (float*)alloc(256 * 4);

  hipMemsetAsync(gbcnt, 0, (size_t)NB * 4, stream);
  hipMemsetAsync(sv, 0, 256 * 4, stream);

  const int* e_src = ei;
  const int* e_dst = ei + E;
  const int EGRID = (E + 4095) / 4096;   // 196
  k_bhist<<<EGRID, 256, 0, stream>>>(e_dst, gbcnt);
  k_bscan<<<1, 256, 0, stream>>>(gbcnt, boff, gcur, offs);
  k_bscatter<<<EGRID, 256, 0, stream>>>(e_src, e_dst, gcur, ebuf);
  k_bbuild<<<NB, 256, 0, stream>>>(ebuf, boff, offs, invd, csr);

  const int LGRID = (N + 63) / 64;   // 782
  auto lin = [&](int nsrc,
                 const void* a0, int f0, int s0, const float* w0, int g0,
                 const void* a1, int f1, int s1, const float* w1_, int g1,
                 const void* a2, int f2, int s2, const float* w2_, int g2,
                 const void* a3, int f3, int s3, const float* w3_, int g3,
                 const void* a4, int f4, int s4, const float* w4_, int g4,
                 const void* a5, int f5, int s5, const float* w5_, int g5,
                 const float* bias, _Float16* op, float* colsum, int relu) {
    LinArgs A;
    A.a[0] = a0; A.a[1] = a1; A.a[2] = a2; A.a[3] = a3; A.a[4] = a4; A.a[5] = a5;
    A.w[0] = w0; A.w[1] = w1_; A.w[2] = w2_; A.w[3] = w3_; A.w[4] = w4_; A.w[5] = w5_;
    A.gidx[0] = g0; A.gidx[1] = g1; A.gidx[2] = g2; A.gidx[3] = g3; A.gidx[4] = g4; A.gidx[5] = g5;
    A.stride[0] = s0; A.stride[1] = s1; A.stride[2] = s2; A.stride[3] = s3; A.stride[4] = s4; A.stride[5] = s5;
    A.isf32[0] = f0; A.isf32[1] = f1; A.isf32[2] = f2; A.isf32[3] = f3; A.isf32[4] = f4; A.isf32[5] = f5;
    A.nsrc = nsrc; A.bias = bias; A.skip = skip;
    A.outp = op; A.colsum = colsum;
    A.n = N; A.relu = relu;
    k_linear<<<LGRID, 256, 0, stream>>>(A);
  };

  // pre_mlp pass1: t0 = relu(nf @ pre_w1 + pre_b1)  (K=128 -> 2 fp32 sources)
  lin(2, nf, 1, 128, pre_w1, -1, nf + 64, 1, 128, pre_w1 + 64 * 64, -1,
      nullptr, 0, 0, nullptr, -1, nullptr, 0, 0, nullptr, -1,
      nullptr, 0, 0, nullptr, -1, nullptr, 0, 0, nullptr, -1,
      pre_b1, t0, nullptr, 1);
  // pre_mlp pass2: x = t0 @ pre_w2 + pre_b2  (fused colsum -> sv[0:64])
  lin(1, t0, 0, 0, pre_w2, -1,
      nullptr, 0, 0, nullptr, -1, nullptr, 0, 0, nullptr, -1,
      nullptr, 0, 0, nullptr, -1, nullptr, 0, 0, nullptr, -1,
      nullptr, 0, 0, nullptr, -1, pre_b2, x, sv, 0);

  // layer 0 (gate skip[0][0] = idx 0 on both agg and root paths)
  k_aggregate<<<(N + 3) / 4, 256, 0, stream>>>(x, offs, csr, invd, m0, N);
  lin(2, m0, 0, 0, wl0, 0, x, 0, 0, wr0, 0,
      nullptr, 0, 0, nullptr, -1, nullptr, 0, 0, nullptr, -1,
      nullptr, 0, 0, nullptr, -1, nullptr, 0, 0, nullptr, -1,
      bl0, h0, sv + 64, 1);

  // layer 1 (gates skip[1][0]=idx3, skip[1][1]=idx4)
  k_aggregate<<<(N + 3) / 4, 256, 0, stream>>>(h0, offs, csr, invd, m1, N);
  lin(4, m0, 0, 0, wl1, 3, m1, 0, 0, wl1 + 64 * 64, 4,
      x, 0, 0, wr1, 3, h0, 0, 0, wr1 + 64 * 64, 4,
      nullptr, 0, 0, nullptr, -1, nullptr, 0, 0, nullptr, -1,
      bl1, h1, sv + 128, 1);

  // layer 2 (gates skip[2][0..2] = idx 6,7,8); output feeds only the colsum
  k_aggregate<<<(N + 3) / 4, 256, 0, stream>>>(h1, offs, csr, invd, m2, N);
  lin(6, m0, 0, 0, wl2, 6, m1, 0, 0, wl2 + 64 * 64, 7, m2, 0, 0, wl2 + 128 * 64, 8,
      x, 0, 0, wr2, 6, h0, 0, 0, wr2 + 64 * 64, 7, h1, 0, 0, wr2 + 128 * 64, 8,
      bl2, nullptr, sv + 192, 1);

  // post-MLP on the fused column sums
  k_post<<<1, 256, 0, stream>>>(sv, pw1, pb1, pw2, pb2, pw3, pb3, pw4, pb4, out);
}

// Round 4
// 356.592 us; speedup vs baseline: 1.0249x; 1.0249x over previous
//
#include <hip/hip_runtime.h>
#include <math.h>

#define NN 50000
#define NE 800000
#define NB 196        // dst buckets of 256 nodes: (NN+255)>>8

typedef float v4f __attribute__((ext_vector_type(4)));
typedef float v2f __attribute__((ext_vector_type(2)));
typedef _Float16 v8h __attribute__((ext_vector_type(8)));

// ---------------- fp8 e4m3fn (OCP) helpers: HW builtins w/ fallback ----------
__device__ __forceinline__ unsigned char enc8(float v) {
#if __has_builtin(__builtin_amdgcn_cvt_pk_fp8_f32)
  return (unsigned char)(__builtin_amdgcn_cvt_pk_fp8_f32(v, v, 0, false) & 0xFF);
#else
  unsigned u = __float_as_uint(v);
  unsigned s = (u >> 24) & 0x80u;
  unsigned au = u & 0x7fffffffu;
  float a = __uint_as_float(au);
  if (au < 0x3C800000u) {               // < 2^-6: denormal zone, step 2^-9
    int m = (int)(a * 512.0f + 0.5f);
    if (m >= 8) return (unsigned char)(s | 8u);
    return (unsigned char)(s | (unsigned)m);
  }
  unsigned r = au + 0x7FFFFu + ((au >> 20) & 1u);   // RNE at mantissa bit 20
  unsigned e = (r >> 23) - 120u;                     // e4m3 bias 7
  unsigned man = (r >> 20) & 7u;
  if (e > 15u) { e = 15u; man = 6u; }                // saturate to 448
  return (unsigned char)(s | (e << 3) | man);
#endif
}

#if __has_builtin(__builtin_amdgcn_cvt_pk_f32_fp8)
#define DEC8_HW 1
#else
__device__ __forceinline__ float dec8_1(unsigned b) {
  unsigned s = (b & 0x80u) << 24;
  unsigned em = b & 0x7fu;
  float v;
  if (em >= 8u) v = __uint_as_float((((em >> 3) + 120u) << 23) | ((em & 7u) << 20));
  else v = (float)em * 0.001953125f;
  return __uint_as_float(__float_as_uint(v) | s);
}
#endif

// decode 8 fp8 bytes (uint2) -> 8 floats
__device__ __forceinline__ void dec8x8(uint2 u, float* f) {
#ifdef DEC8_HW
  v2f p0 = __builtin_amdgcn_cvt_pk_f32_fp8((int)u.x, false);
  v2f p1 = __builtin_amdgcn_cvt_pk_f32_fp8((int)u.x, true);
  v2f p2 = __builtin_amdgcn_cvt_pk_f32_fp8((int)u.y, false);
  v2f p3 = __builtin_amdgcn_cvt_pk_f32_fp8((int)u.y, true);
  f[0] = p0.x; f[1] = p0.y; f[2] = p1.x; f[3] = p1.y;
  f[4] = p2.x; f[5] = p2.y; f[6] = p3.x; f[7] = p3.y;
#else
#pragma unroll
  for (int i = 0; i < 4; ++i) f[i] = dec8_1((u.x >> (8 * i)) & 0xFF);
#pragma unroll
  for (int i = 0; i < 4; ++i) f[4 + i] = dec8_1((u.y >> (8 * i)) & 0xFF);
#endif
}

// ================= graph build: two-level bucket sort (dense writes) ==========

__global__ __launch_bounds__(256) void k_bhist(const int* __restrict__ dst,
                                               int* __restrict__ gbcnt) {
  __shared__ int lcnt[NB];
  int t = threadIdx.x;
  for (int i = t; i < NB; i += 256) lcnt[i] = 0;
  __syncthreads();
  int eb = blockIdx.x * 4096;
#pragma unroll
  for (int i = 0; i < 16; ++i) {
    int e = eb + i * 256 + t;
    if (e < NE) atomicAdd(&lcnt[dst[e] >> 8], 1);
  }
  __syncthreads();
  for (int i = t; i < NB; i += 256)
    if (lcnt[i]) atomicAdd(&gbcnt[i], lcnt[i]);
}

// scan bucket counts -> boff[NB+1]; init cursors; offs[NN]=NE; zero sv
__global__ __launch_bounds__(256) void k_bscan(const int* __restrict__ gbcnt,
                                               int* __restrict__ boff,
                                               int* __restrict__ gcur,
                                               int* __restrict__ offs,
                                               float* __restrict__ sv) {
  __shared__ int sd[256];
  int t = threadIdx.x;
  sv[t] = 0.f;                 // fused sv zeroing (256 floats)
  int v = (t < NB) ? gbcnt[t] : 0;
  sd[t] = v;
  __syncthreads();
  for (int o = 1; o < 256; o <<= 1) {
    int u = (t >= o) ? sd[t - o] : 0;
    __syncthreads();
    sd[t] += u;
    __syncthreads();
  }
  if (t < NB) { int x = sd[t] - v; boff[t] = x; gcur[t] = x; }
  if (t == NB - 1) boff[NB] = sd[t];
  if (t == 0) offs[NN] = NE;
}

__global__ __launch_bounds__(256) void k_bscatter(const int* __restrict__ src,
                                                  const int* __restrict__ dst,
                                                  int* __restrict__ gcur,
                                                  unsigned* __restrict__ ebuf) {
  __shared__ int cnt[NB];
  __shared__ int base[NB];
  int t = threadIdx.x;
  for (int i = t; i < NB; i += 256) cnt[i] = 0;
  __syncthreads();
  int eb = blockIdx.x * 4096;
  unsigned pk[16];
  int bk[16], lp[16];
#pragma unroll
  for (int i = 0; i < 16; ++i) {
    int e = eb + i * 256 + t;
    if (e < NE) {
      int d = dst[e];
      int b = d >> 8;
      pk[i] = ((unsigned)src[e] << 8) | (unsigned)(d & 255);
      bk[i] = b;
      lp[i] = atomicAdd(&cnt[b], 1);
    }
  }
  __syncthreads();
  for (int i = t; i < NB; i += 256)
    base[i] = cnt[i] ? atomicAdd(&gcur[i], cnt[i]) : 0;
  __syncthreads();
#pragma unroll
  for (int i = 0; i < 16; ++i) {
    int e = eb + i * 256 + t;
    if (e < NE) ebuf[base[bk[i]] + lp[i]] = pk[i];
  }
}

__global__ __launch_bounds__(256) void k_bbuild(const unsigned* __restrict__ ebuf,
                                                const int* __restrict__ boff,
                                                int* __restrict__ offs,
                                                float* __restrict__ invd,
                                                int* __restrict__ csr) {
  __shared__ int dcnt[256];
  __shared__ int cur[256];
  int t = threadIdx.x;
  int b = blockIdx.x;
  int node0 = b << 8;
  int es = boff[b], ee = boff[b + 1];
  dcnt[t] = 0;
  __syncthreads();
  for (int e = es + t; e < ee; e += 256) atomicAdd(&dcnt[ebuf[e] & 255], 1);
  __syncthreads();
  int v = dcnt[t];
  cur[t] = v;
  __syncthreads();
  for (int o = 1; o < 256; o <<= 1) {
    int u = (t >= o) ? cur[t - o] : 0;
    __syncthreads();
    cur[t] += u;
    __syncthreads();
  }
  int excl = cur[t] - v;
  int node = node0 + t;
  if (node < NN) {
    offs[node] = es + excl;
    invd[node] = 1.0f / fmaxf((float)v, 1.0f);
  }
  __syncthreads();
  cur[t] = es + excl;
  __syncthreads();
  for (int e = es + t; e < ee; e += 256) {
    unsigned pk = ebuf[e];
    int p = atomicAdd(&cur[pk & 255], 1);
    csr[p] = (int)(pk >> 8);
  }
}

// ================= per-node mean aggregation (fp8 gather rows) ================
// feat: [n][64] fp8 -> 64B/row; 3.2MB table fits each XCD's 4MB L2.
// lane = slot*8 + cg; 16 rows in flight (8 slots x 2-deep).
// mean written fp16 [n][64] for the MFMA A-path.
__global__ __launch_bounds__(256) void k_aggregate(
    const unsigned char* __restrict__ feat,
    const int* __restrict__ offs, const int* __restrict__ csr,
    const float* __restrict__ invd,
    _Float16* __restrict__ mean, int n) {
  int node = blockIdx.x * 4 + (threadIdx.x >> 6);
  int lane = threadIdx.x & 63;
  int slot = lane >> 3;     // 0..7 neighbor slot
  int cg   = lane & 7;      // 8 groups x 8 bytes = full 64B row
  if (node >= n) return;
  int s = offs[node], e = offs[node + 1];

  float a[8];
#pragma unroll
  for (int i = 0; i < 8; ++i) a[i] = 0.f;

  if (e > s) {
    int emax = e - 1;
    for (int p0 = s; p0 < e; p0 += 16) {
      int pa = p0 + slot, pb = p0 + 8 + slot;
      int ja = __builtin_nontemporal_load(csr + (pa < emax ? pa : emax));
      int jb = __builtin_nontemporal_load(csr + (pb < emax ? pb : emax));
      uint2 ua = *(const uint2*)(feat + (size_t)ja * 64 + cg * 8);
      uint2 ub = *(const uint2*)(feat + (size_t)jb * 64 + cg * 8);
      float fa[8], fb[8];
      dec8x8(ua, fa);
      dec8x8(ub, fb);
      if (pa < e) {
#pragma unroll
        for (int i = 0; i < 8; ++i) a[i] += fa[i];
      }
      if (pb < e) {
#pragma unroll
        for (int i = 0; i < 8; ++i) a[i] += fb[i];
      }
    }
  }
#pragma unroll
  for (int i = 0; i < 8; ++i) {
    a[i] += __shfl_xor(a[i], 8, 64);   // fold slot bit0
    a[i] += __shfl_xor(a[i], 16, 64);  // slot bit1
    a[i] += __shfl_xor(a[i], 32, 64);  // slot bit2
  }
  if (lane < 8) {
    float d = invd[node];
    v8h o;
#pragma unroll
    for (int i = 0; i < 8; ++i) o[i] = (_Float16)(a[i] * d);
    *(v8h*)(mean + (size_t)node * 64 + lane * 8) = o;
  }
}

// ================= fused multi-source linear, MFMA fp16 =======================
// out = act( sum_s A_s @ (g_s W_s) + bias );  A fp16 rows, W split-fp16 hi+lo.
struct LinArgs {
  const _Float16* a[6];    // fp16 [n][64] row ptrs
  const float* w[6];       // [64][64] fp32 blocks (row stride 64)
  int gidx[6];
  int nsrc;
  const float* bias;
  const float* skip;
  _Float16* outp;          // [n][64] fp16, or nullptr
  unsigned char* out8;     // [n][64] fp8 gather copy, or nullptr
  float* colsum;           // [64] atomic target, or nullptr
  int n;
  int relu;
};

__global__ __launch_bounds__(256) void k_linear(LinArgs A) {
  __shared__ _Float16 sW[2][2][64 * 72];   // [buf][hi/lo][n*72+k]
  const int t    = threadIdx.x;
  const int lane = t & 63;
  const int wv   = t >> 6;
  const int qd   = lane >> 4;
  const int ln   = lane & 15;
  const int n0   = blockIdx.x * 64;

  v4f acc[4];
#pragma unroll
  for (int ct = 0; ct < 4; ++ct) acc[ct] = (v4f){0.f, 0.f, 0.f, 0.f};

  const int sn = t & 63;
  float wreg[16];
  auto loadW = [&](int s) {
    const float* w = A.w[s];
#pragma unroll
    for (int c = 0; c < 2; ++c) {
      int kb = (wv + 4 * c) * 8;
#pragma unroll
      for (int j = 0; j < 8; ++j)
        wreg[c * 8 + j] = w[(size_t)(kb + j) * 64 + sn];
    }
  };
  auto writeW = [&](int s, int b) {
    float gs = 1.0f;
    if (A.gidx[s] >= 0) gs = 1.0f / (1.0f + __expf(-A.skip[A.gidx[s]]));
#pragma unroll
    for (int c = 0; c < 2; ++c) {
      int cb = wv + 4 * c;
      v8h hv, lv;
#pragma unroll
      for (int j = 0; j < 8; ++j) {
        float f = wreg[c * 8 + j] * gs;
        _Float16 h = (_Float16)f;
        hv[j] = h;
        lv[j] = (_Float16)(f - (float)h);
      }
      *(v8h*)(&sW[b][0][sn * 72 + cb * 8]) = hv;
      *(v8h*)(&sW[b][1][sn * 72 + cb * 8]) = lv;
    }
  };

  const int arow = n0 + wv * 16 + ln;
  const bool arv = arow < A.n;
  v8h ah[2];
  auto loadA = [&](int s) {
    const _Float16* ph = A.a[s] + (size_t)arow * 64;
    if (arv) {
#pragma unroll
      for (int ks = 0; ks < 2; ++ks)
        ah[ks] = *(const v8h*)(ph + ks * 32 + qd * 8);
    } else {
      v8h z;
#pragma unroll
      for (int j = 0; j < 8; ++j) z[j] = (_Float16)0.f;
      ah[0] = ah[1] = z;
    }
  };

  loadW(0);
  writeW(0, 0);
  __syncthreads();

  for (int s = 0; s < A.nsrc; ++s) {
    loadA(s);
    if (s + 1 < A.nsrc) loadW(s + 1);
    const _Float16* wh = &sW[s & 1][0][0];
    const _Float16* wl = &sW[s & 1][1][0];
#pragma unroll
    for (int ks = 0; ks < 2; ++ks) {
#pragma unroll
      for (int ct = 0; ct < 4; ++ct) {
        int wn = ct * 16 + ln;
        v8h bh = *(const v8h*)(wh + wn * 72 + ks * 32 + qd * 8);
        v8h bl = *(const v8h*)(wl + wn * 72 + ks * 32 + qd * 8);
        acc[ct] = __builtin_amdgcn_mfma_f32_16x16x32_f16(ah[ks], bh, acc[ct], 0, 0, 0);
        acc[ct] = __builtin_amdgcn_mfma_f32_16x16x32_f16(ah[ks], bl, acc[ct], 0, 0, 0);
      }
    }
    if (s + 1 < A.nsrc) writeW(s + 1, (s + 1) & 1);
    __syncthreads();
  }

  float bvals[4];
#pragma unroll
  for (int ct = 0; ct < 4; ++ct) bvals[ct] = A.bias[ct * 16 + ln];

  unsigned char* f8t = (unsigned char*)&sW[1][0][0];   // 4KB fp8 tile
  float* red = (float*)&sW[0][0][0];                    // colsum scratch

  float cs[4] = {0.f, 0.f, 0.f, 0.f};
#pragma unroll
  for (int ct = 0; ct < 4; ++ct) {
#pragma unroll
    for (int r = 0; r < 4; ++r) {
      int nb = wv * 16 + qd * 4 + r;      // row in tile
      int node = n0 + nb;                  // C/D: row=(lane>>4)*4+reg, col=lane&15
      float v = acc[ct][r] + bvals[ct];
      if (A.relu) v = fmaxf(v, 0.f);
      if (node < A.n) {
        if (A.outp) A.outp[(size_t)node * 64 + ct * 16 + ln] = (_Float16)v;
        if (A.out8) f8t[nb * 64 + ct * 16 + ln] = enc8(v);
        cs[ct] += v;
      }
    }
  }
  if (A.colsum) {
#pragma unroll
    for (int ct = 0; ct < 4; ++ct) {
      float v = cs[ct];
      v += __shfl_xor(v, 16, 64);
      v += __shfl_xor(v, 32, 64);
      if (qd == 0) red[wv * 64 + ct * 16 + ln] = v;
    }
  }
  if (A.out8 || A.colsum) __syncthreads();
  if (A.out8) {
    int row = t >> 2, ch = t & 3;
    if (n0 + row < A.n) {
      uint4 val = *(const uint4*)(f8t + row * 64 + ch * 16);
      *(uint4*)(A.out8 + (size_t)(n0 + row) * 64 + ch * 16) = val;
    }
  }
  if (A.colsum && t < 64) {
    float ssum = red[t] + red[64 + t] + red[128 + t] + red[192 + t];
    atomicAdd(&A.colsum[t], ssum);
  }
}

// ============== fused pre-MLP: x = (relu(nf@W1+b1))@W2 + b2 ===================
// Stage1 (K=128, fp32 A) -> LDS fp16 tile -> Stage2 -> x fp16 + x fp8 + colsum.
__global__ __launch_bounds__(256) void k_pre(
    const float* __restrict__ nf,
    const float* __restrict__ w1, const float* __restrict__ b1,
    const float* __restrict__ w2, const float* __restrict__ b2,
    _Float16* __restrict__ xout, unsigned char* __restrict__ x8,
    float* __restrict__ colsum, int n) {
  __shared__ _Float16 sW[2][2][64 * 72];
  __shared__ _Float16 atile[64 * 72];
  const int t    = threadIdx.x;
  const int lane = t & 63;
  const int wv   = t >> 6;
  const int qd   = lane >> 4;
  const int ln   = lane & 15;
  const int n0   = blockIdx.x * 64;
  const int sn   = t & 63;

  float wreg[16];
  auto loadW = [&](const float* w) {
#pragma unroll
    for (int c = 0; c < 2; ++c) {
      int kb = (wv + 4 * c) * 8;
#pragma unroll
      for (int j = 0; j < 8; ++j)
        wreg[c * 8 + j] = w[(size_t)(kb + j) * 64 + sn];
    }
  };
  auto writeW = [&](int b) {
#pragma unroll
    for (int c = 0; c < 2; ++c) {
      int cb = wv + 4 * c;
      v8h hv, lv;
#pragma unroll
      for (int j = 0; j < 8; ++j) {
        float f = wreg[c * 8 + j];
        _Float16 h = (_Float16)f;
        hv[j] = h;
        lv[j] = (_Float16)(f - (float)h);
      }
      *(v8h*)(&sW[b][0][sn * 72 + cb * 8]) = hv;
      *(v8h*)(&sW[b][1][sn * 72 + cb * 8]) = lv;
    }
  };

  const int arow = n0 + wv * 16 + ln;
  const bool arv = arow < n;
  v4f acc[4];
#pragma unroll
  for (int ct = 0; ct < 4; ++ct) acc[ct] = (v4f){0.f, 0.f, 0.f, 0.f};
  v8h ah[2];

  auto loadAf32 = [&](const float* base) {
#pragma unroll
    for (int ks = 0; ks < 2; ++ks) {
      v8h hv;
      if (arv) {
        const float* p = base + (size_t)arow * 128 + ks * 32 + qd * 8;
        float4 u0 = *(const float4*)(p);
        float4 u1 = *(const float4*)(p + 4);
        hv[0] = (_Float16)u0.x; hv[1] = (_Float16)u0.y;
        hv[2] = (_Float16)u0.z; hv[3] = (_Float16)u0.w;
        hv[4] = (_Float16)u1.x; hv[5] = (_Float16)u1.y;
        hv[6] = (_Float16)u1.z; hv[7] = (_Float16)u1.w;
      } else {
#pragma unroll
        for (int j = 0; j < 8; ++j) hv[j] = (_Float16)0.f;
      }
      ah[ks] = hv;
    }
  };
  auto domfma = [&](int b) {
    const _Float16* wh = &sW[b][0][0];
    const _Float16* wl = &sW[b][1][0];
#pragma unroll
    for (int ks = 0; ks < 2; ++ks) {
#pragma unroll
      for (int ct = 0; ct < 4; ++ct) {
        int wn = ct * 16 + ln;
        v8h bh = *(const v8h*)(wh + wn * 72 + ks * 32 + qd * 8);
        v8h bl = *(const v8h*)(wl + wn * 72 + ks * 32 + qd * 8);
        acc[ct] = __builtin_amdgcn_mfma_f32_16x16x32_f16(ah[ks], bh, acc[ct], 0, 0, 0);
        acc[ct] = __builtin_amdgcn_mfma_f32_16x16x32_f16(ah[ks], bl, acc[ct], 0, 0, 0);
      }
    }
  };

  // stage 1: t0 = relu(nf@W1 + b1), K=128 as two 64-col sources
  loadW(w1);
  writeW(0);
  __syncthreads();
  loadAf32(nf);
  loadW(w1 + 64 * 64);
  domfma(0);
  writeW(1);
  __syncthreads();
  loadAf32(nf + 64);
  loadW(w2);
  domfma(1);
  writeW(0);          // W2 into buf0 (buf0 reads completed before last barrier)

  float b1v[4];
#pragma unroll
  for (int ct = 0; ct < 4; ++ct) b1v[ct] = b1[ct * 16 + ln];
#pragma unroll
  for (int ct = 0; ct < 4; ++ct) {
#pragma unroll
    for (int r = 0; r < 4; ++r) {
      int nb = wv * 16 + qd * 4 + r;
      float v = fmaxf(acc[ct][r] + b1v[ct], 0.f);
      atile[nb * 72 + ct * 16 + ln] = (_Float16)v;
    }
  }
#pragma unroll
  for (int ct = 0; ct < 4; ++ct) acc[ct] = (v4f){0.f, 0.f, 0.f, 0.f};
  __syncthreads();

  // stage 2: x = t0 @ W2 + b2
  const int trow = wv * 16 + ln;
#pragma unroll
  for (int ks = 0; ks < 2; ++ks)
    ah[ks] = *(const v8h*)(atile + trow * 72 + ks * 32 + qd * 8);
  domfma(0);

  float b2v[4];
#pragma unroll
  for (int ct = 0; ct < 4; ++ct) b2v[ct] = b2[ct * 16 + ln];

  unsigned char* f8t = (unsigned char*)&sW[1][0][0];
  float* red = (float*)&sW[0][0][0];
  float cs[4] = {0.f, 0.f, 0.f, 0.f};
  __syncthreads();   // atile reads done; sW reuse safe
#pragma unroll
  for (int ct = 0; ct < 4; ++ct) {
#pragma unroll
    for (int r = 0; r < 4; ++r) {
      int nb = wv * 16 + qd * 4 + r;
      int node = n0 + nb;
      float v = acc[ct][r] + b2v[ct];
      if (node < n) {
        xout[(size_t)node * 64 + ct * 16 + ln] = (_Float16)v;
        f8t[nb * 64 + ct * 16 + ln] = enc8(v);
        cs[ct] += v;
      }
    }
  }
#pragma unroll
  for (int ct = 0; ct < 4; ++ct) {
    float v = cs[ct];
    v += __shfl_xor(v, 16, 64);
    v += __shfl_xor(v, 32, 64);
    if (qd == 0) red[wv * 64 + ct * 16 + ln] = v;
  }
  __syncthreads();
  {
    int row = t >> 2, ch = t & 3;
    if (n0 + row < n) {
      uint4 val = *(const uint4*)(f8t + row * 64 + ch * 16);
      *(uint4*)(x8 + (size_t)(n0 + row) * 64 + ch * 16) = val;
    }
  }
  if (t < 64) {
    float ssum = red[t] + red[64 + t] + red[128 + t] + red[192 + t];
    atomicAdd(&colsum[t], ssum);
  }
}

// ---------------- tiny post-MLP (single block) ----------------
__global__ __launch_bounds__(256) void k_post(const float* __restrict__ s,
                                              const float* __restrict__ w1, const float* __restrict__ b1,
                                              const float* __restrict__ w2, const float* __restrict__ b2,
                                              const float* __restrict__ w3, const float* __restrict__ b3,
                                              const float* __restrict__ w4, const float* __restrict__ b4,
                                              float* __restrict__ outp) {
  __shared__ float sh[256], h1[64], h2[64], h3[256];
  int t = threadIdx.x;
  sh[t] = s[t];
  __syncthreads();
  if (t < 64) {
    float a = b1[t];
    for (int k = 0; k < 256; ++k) a += sh[k] * w1[k * 64 + t];
    h1[t] = (a >= 0.f) ? a : 0.1f * a;   // leaky_relu 0.1
  }
  __syncthreads();
  if (t < 64) {
    float a = b2[t];
    for (int k = 0; k < 64; ++k) a += h1[k] * w2[k * 64 + t];
    h2[t] = fmaxf(a, 0.f);
  }
  __syncthreads();
  {
    float a = b3[t];
    for (int k = 0; k < 64; ++k) a += h2[k] * w3[k * 256 + t];
    h3[t] = fmaxf(a, 0.f);
  }
  __syncthreads();
  if (t < 64) {
    float a = b4[t];
    for (int k = 0; k < 256; ++k) a += h3[k] * w4[k * 64 + t];
    outp[t] = a;
  }
}

extern "C" void kernel_launch(void* const* d_in, const int* in_sizes, int n_in,
                              void* d_out, int out_size, void* d_ws, size_t ws_size,
                              hipStream_t stream) {
  const float* nf     = (const float*)d_in[0];
  const int*   ei     = (const int*)d_in[1];
  const float* pre_w1 = (const float*)d_in[2];
  const float* pre_b1 = (const float*)d_in[3];
  const float* pre_w2 = (const float*)d_in[4];
  const float* pre_b2 = (const float*)d_in[5];
  const float* skip   = (const float*)d_in[6];
  const float* wl0 = (const float*)d_in[7],  *bl0 = (const float*)d_in[8],  *wr0 = (const float*)d_in[9];
  const float* wl1 = (const float*)d_in[10], *bl1 = (const float*)d_in[11], *wr1 = (const float*)d_in[12];
  const float* wl2 = (const float*)d_in[13], *bl2 = (const float*)d_in[14], *wr2 = (const float*)d_in[15];
  const float* pw1 = (const float*)d_in[16], *pb1 = (const float*)d_in[17];
  const float* pw2 = (const float*)d_in[18], *pb2 = (const float*)d_in[19];
  const float* pw3 = (const float*)d_in[20], *pb3 = (const float*)d_in[21];
  const float* pw4 = (const float*)d_in[22], *pb4 = (const float*)d_in[23];
  float* out = (float*)d_out;

  const int N = NN, E = NE;

  // workspace carve-up
  char* ws = (char*)d_ws;
  size_t pos = 0;
  auto alloc = [&](size_t bytes) {
    char* p = ws + pos;
    pos += (bytes + 255) & ~(size_t)255;
    return (void*)p;
  };
  int*      gbcnt = (int*)alloc((size_t)NB * 4);
  int*      boff  = (int*)alloc((size_t)(NB + 1) * 4);
  int*      gcur  = (int*)alloc((size_t)NB * 4);
  unsigned* ebuf  = (unsigned*)alloc((size_t)E * 4);
  int*      offs  = (int*)alloc((size_t)(N + 1) * 4);
  float*    invd  = (float*)alloc((size_t)N * 4);
  int*      csr   = (int*)alloc((size_t)E * 4);
  const size_t PB = (size_t)N * 64 * 2;   // fp16 rows, bytes
  _Float16* x  = (_Float16*)alloc(PB);
  _Float16* h0 = (_Float16*)alloc(PB);
  _Float16* h1 = (_Float16*)alloc(PB);
  _Float16* m0 = (_Float16*)alloc(PB);
  _Float16* m1 = (_Float16*)alloc(PB);
  _Float16* m2 = (_Float16*)alloc(PB);
  unsigned char* f8 = (unsigned char*)alloc((size_t)N * 64);  // rotating gather table
  float* sv = (float*)alloc(256 * 4);

  hipMemsetAsync(gbcnt, 0, (size_t)NB * 4, stream);

  const int* e_src = ei;
  const int* e_dst = ei + E;
  const int EGRID = (E + 4095) / 4096;   // 196
  k_bhist<<<EGRID, 256, 0, stream>>>(e_dst, gbcnt);
  k_bscan<<<1, 256, 0, stream>>>(gbcnt, boff, gcur, offs, sv);
  k_bscatter<<<EGRID, 256, 0, stream>>>(e_src, e_dst, gcur, ebuf);
  k_bbuild<<<NB, 256, 0, stream>>>(ebuf, boff, offs, invd, csr);

  const int LGRID = (N + 63) / 64;   // 782
  auto lin = [&](int nsrc,
                 const _Float16* a0, const float* w0, int g0,
                 const _Float16* a1, const float* w1_, int g1,
                 const _Float16* a2, const float* w2_, int g2,
                 const _Float16* a3, const float* w3_, int g3,
                 const _Float16* a4, const float* w4_, int g4,
                 const _Float16* a5, const float* w5_, int g5,
                 const float* bias, _Float16* op, unsigned char* o8,
                 float* colsum, int relu) {
    LinArgs A;
    A.a[0] = a0; A.a[1] = a1; A.a[2] = a2; A.a[3] = a3; A.a[4] = a4; A.a[5] = a5;
    A.w[0] = w0; A.w[1] = w1_; A.w[2] = w2_; A.w[3] = w3_; A.w[4] = w4_; A.w[5] = w5_;
    A.gidx[0] = g0; A.gidx[1] = g1; A.gidx[2] = g2; A.gidx[3] = g3; A.gidx[4] = g4; A.gidx[5] = g5;
    A.nsrc = nsrc; A.bias = bias; A.skip = skip;
    A.outp = op; A.out8 = o8; A.colsum = colsum;
    A.n = N; A.relu = relu;
    k_linear<<<LGRID, 256, 0, stream>>>(A);
  };

  // fused pre-MLP: x (fp16 + fp8) + colsum sv[0:64]
  k_pre<<<LGRID, 256, 0, stream>>>(nf, pre_w1, pre_b1, pre_w2, pre_b2,
                                   x, f8, sv, N);

  // layer 0 (gate skip[0][0] = idx 0)
  k_aggregate<<<(N + 3) / 4, 256, 0, stream>>>(f8, offs, csr, invd, m0, N);
  lin(2, m0, wl0, 0, x, wr0, 0,
      nullptr, nullptr, -1, nullptr, nullptr, -1,
      nullptr, nullptr, -1, nullptr, nullptr, -1,
      bl0, h0, f8, sv + 64, 1);

  // layer 1 (gates skip[1][0]=idx3, skip[1][1]=idx4)
  k_aggregate<<<(N + 3) / 4, 256, 0, stream>>>(f8, offs, csr, invd, m1, N);
  lin(4, m0, wl1, 3, m1, wl1 + 64 * 64, 4,
      x, wr1, 3, h0, wr1 + 64 * 64, 4,
      nullptr, nullptr, -1, nullptr, nullptr, -1,
      bl1, h1, f8, sv + 128, 1);

  // layer 2 (gates skip[2][0..2] = idx 6,7,8); colsum only
  k_aggregate<<<(N + 3) / 4, 256, 0, stream>>>(f8, offs, csr, invd, m2, N);
  lin(6, m0, wl2, 6, m1, wl2 + 64 * 64, 7, m2, wl2 + 128 * 64, 8,
      x, wr2, 6, h0, wr2 + 64 * 64, 7, h1, wr2 + 128 * 64, 8,
      bl2, nullptr, nullptr, sv + 192, 1);

  // post-MLP on the fused column sums
  k_post<<<1, 256, 0, stream>>>(sv, pw1, pb1, pw2, pb2, pw3, pb3, pw4, pb4, out);
}

// Round 5
// 333.215 us; speedup vs baseline: 1.0968x; 1.0702x over previous
//
#include <hip/hip_runtime.h>
#include <math.h>

#define NN 50000
#define NE 800000
#define NB 196        // dst buckets of 256 nodes: (NN+255)>>8

typedef float v4f __attribute__((ext_vector_type(4)));
typedef float v2f __attribute__((ext_vector_type(2)));
typedef _Float16 v8h __attribute__((ext_vector_type(8)));

// ---------------- fp8 e4m3fn (OCP) helpers: HW builtins w/ fallback ----------
__device__ __forceinline__ unsigned char enc8(float v) {
#if __has_builtin(__builtin_amdgcn_cvt_pk_fp8_f32)
  return (unsigned char)(__builtin_amdgcn_cvt_pk_fp8_f32(v, v, 0, false) & 0xFF);
#else
  unsigned u = __float_as_uint(v);
  unsigned s = (u >> 24) & 0x80u;
  unsigned au = u & 0x7fffffffu;
  float a = __uint_as_float(au);
  if (au < 0x3C800000u) {               // < 2^-6: denormal zone, step 2^-9
    int m = (int)(a * 512.0f + 0.5f);
    if (m >= 8) return (unsigned char)(s | 8u);
    return (unsigned char)(s | (unsigned)m);
  }
  unsigned r = au + 0x7FFFFu + ((au >> 20) & 1u);   // RNE at mantissa bit 20
  unsigned e = (r >> 23) - 120u;                     // e4m3 bias 7
  unsigned man = (r >> 20) & 7u;
  if (e > 15u) { e = 15u; man = 6u; }                // saturate to 448
  return (unsigned char)(s | (e << 3) | man);
#endif
}

#if __has_builtin(__builtin_amdgcn_cvt_pk_f32_fp8)
#define DEC8_HW 1
#else
__device__ __forceinline__ float dec8_1(unsigned b) {
  unsigned s = (b & 0x80u) << 24;
  unsigned em = b & 0x7fu;
  float v;
  if (em >= 8u) v = __uint_as_float((((em >> 3) + 120u) << 23) | ((em & 7u) << 20));
  else v = (float)em * 0.001953125f;
  return __uint_as_float(__float_as_uint(v) | s);
}
#endif

// decode 8 fp8 bytes (uint2) -> 8 floats
__device__ __forceinline__ void dec8x8(uint2 u, float* f) {
#ifdef DEC8_HW
  v2f p0 = __builtin_amdgcn_cvt_pk_f32_fp8((int)u.x, false);
  v2f p1 = __builtin_amdgcn_cvt_pk_f32_fp8((int)u.x, true);
  v2f p2 = __builtin_amdgcn_cvt_pk_f32_fp8((int)u.y, false);
  v2f p3 = __builtin_amdgcn_cvt_pk_f32_fp8((int)u.y, true);
  f[0] = p0.x; f[1] = p0.y; f[2] = p1.x; f[3] = p1.y;
  f[4] = p2.x; f[5] = p2.y; f[6] = p3.x; f[7] = p3.y;
#else
#pragma unroll
  for (int i = 0; i < 4; ++i) f[i] = dec8_1((u.x >> (8 * i)) & 0xFF);
#pragma unroll
  for (int i = 0; i < 4; ++i) f[4 + i] = dec8_1((u.y >> (8 * i)) & 0xFF);
#endif
}
// decode 16 fp8 bytes (uint4) -> 16 floats
__device__ __forceinline__ void dec8x16(uint4 u, float* f) {
  dec8x8(make_uint2(u.x, u.y), f);
  dec8x8(make_uint2(u.z, u.w), f + 8);
}

// ================= graph build: two-level bucket sort (dense writes) ==========

__global__ __launch_bounds__(256) void k_bhist(const int* __restrict__ dst,
                                               int* __restrict__ gbcnt) {
  __shared__ int lcnt[NB];
  int t = threadIdx.x;
  for (int i = t; i < NB; i += 256) lcnt[i] = 0;
  __syncthreads();
  int eb = blockIdx.x * 4096;
#pragma unroll
  for (int i = 0; i < 16; ++i) {
    int e = eb + i * 256 + t;
    if (e < NE) atomicAdd(&lcnt[dst[e] >> 8], 1);
  }
  __syncthreads();
  for (int i = t; i < NB; i += 256)
    if (lcnt[i]) atomicAdd(&gbcnt[i], lcnt[i]);
}

// scan bucket counts -> boff[NB+1]; init cursors; offs[NN]=NE; zero sv
__global__ __launch_bounds__(256) void k_bscan(const int* __restrict__ gbcnt,
                                               int* __restrict__ boff,
                                               int* __restrict__ gcur,
                                               int* __restrict__ offs,
                                               float* __restrict__ sv) {
  __shared__ int sd[256];
  int t = threadIdx.x;
  sv[t] = 0.f;                 // fused sv zeroing (256 floats)
  int v = (t < NB) ? gbcnt[t] : 0;
  sd[t] = v;
  __syncthreads();
  for (int o = 1; o < 256; o <<= 1) {
    int u = (t >= o) ? sd[t - o] : 0;
    __syncthreads();
    sd[t] += u;
    __syncthreads();
  }
  if (t < NB) { int x = sd[t] - v; boff[t] = x; gcur[t] = x; }
  if (t == NB - 1) boff[NB] = sd[t];
  if (t == 0) offs[NN] = NE;
}

__global__ __launch_bounds__(256) void k_bscatter(const int* __restrict__ src,
                                                  const int* __restrict__ dst,
                                                  int* __restrict__ gcur,
                                                  unsigned* __restrict__ ebuf) {
  __shared__ int cnt[NB];
  __shared__ int base[NB];
  int t = threadIdx.x;
  for (int i = t; i < NB; i += 256) cnt[i] = 0;
  __syncthreads();
  int eb = blockIdx.x * 4096;
  unsigned pk[16];
  int bk[16], lp[16];
#pragma unroll
  for (int i = 0; i < 16; ++i) {
    int e = eb + i * 256 + t;
    if (e < NE) {
      int d = dst[e];
      int b = d >> 8;
      pk[i] = ((unsigned)src[e] << 8) | (unsigned)(d & 255);
      bk[i] = b;
      lp[i] = atomicAdd(&cnt[b], 1);
    }
  }
  __syncthreads();
  for (int i = t; i < NB; i += 256)
    base[i] = cnt[i] ? atomicAdd(&gcur[i], cnt[i]) : 0;
  __syncthreads();
#pragma unroll
  for (int i = 0; i < 16; ++i) {
    int e = eb + i * 256 + t;
    if (e < NE) ebuf[base[bk[i]] + lp[i]] = pk[i];
  }
}

__global__ __launch_bounds__(256) void k_bbuild(const unsigned* __restrict__ ebuf,
                                                const int* __restrict__ boff,
                                                int* __restrict__ offs,
                                                float* __restrict__ invd,
                                                int* __restrict__ csr) {
  __shared__ int dcnt[256];
  __shared__ int cur[256];
  int t = threadIdx.x;
  int b = blockIdx.x;
  int node0 = b << 8;
  int es = boff[b], ee = boff[b + 1];
  dcnt[t] = 0;
  __syncthreads();
  for (int e = es + t; e < ee; e += 256) atomicAdd(&dcnt[ebuf[e] & 255], 1);
  __syncthreads();
  int v = dcnt[t];
  cur[t] = v;
  __syncthreads();
  for (int o = 1; o < 256; o <<= 1) {
    int u = (t >= o) ? cur[t - o] : 0;
    __syncthreads();
    cur[t] += u;
    __syncthreads();
  }
  int excl = cur[t] - v;
  int node = node0 + t;
  if (node < NN) {
    offs[node] = es + excl;
    invd[node] = 1.0f / fmaxf((float)v, 1.0f);
  }
  __syncthreads();
  cur[t] = es + excl;
  __syncthreads();
  for (int e = es + t; e < ee; e += 256) {
    unsigned pk = ebuf[e];
    int p = atomicAdd(&cur[pk & 255], 1);
    csr[p] = (int)(pk >> 8);
  }
}

// ========== fused mean-aggregate + multi-source linear, MFMA fp16 =============
// Phase A (if fusedsrc>=0): gather fp8 rows for this block's 64 nodes, mean in
// fp32, deposit fp16 into LDS atile (the MFMA A-tile) + optional global copy.
// Phase B: out = act( sum_s A_s @ (g_s W_s) + bias ); A fp16, W split-fp16.
struct LinArgs {
  const _Float16* a[6];    // fp16 [n][64] row ptrs (a[fusedsrc] unused)
  const float* w[6];       // [64][64] fp32 blocks (row stride 64)
  int gidx[6];
  int nsrc;
  int fusedsrc;            // which source comes from the in-kernel gather (-1 none)
  const unsigned char* feat8;  // fp8 gather table [n][64]
  const int* offs;
  const int* csr;
  const float* invd;
  _Float16* mout;          // global fp16 copy of fused mean, or nullptr
  const float* bias;
  const float* skip;
  _Float16* outp;          // [n][64] fp16, or nullptr
  unsigned char* out8;     // [n][64] fp8 gather copy, or nullptr
  float* colsum;           // [64] atomic target, or nullptr
  int n;
  int relu;
};

__global__ __launch_bounds__(256) void k_linear(LinArgs A) {
  __shared__ _Float16 sW[2][2][64 * 72];   // [buf][hi/lo][n*72+k]
  __shared__ _Float16 atile[64 * 72];      // fused-mean A tile
  const int t    = threadIdx.x;
  const int lane = t & 63;
  const int wv   = t >> 6;
  const int qd   = lane >> 4;
  const int ln   = lane & 15;
  const int n0   = blockIdx.x * 64;

  const int sn = t & 63;
  float wreg[16];
  auto loadW = [&](int s) {
    const float* w = A.w[s];
#pragma unroll
    for (int c = 0; c < 2; ++c) {
      int kb = (wv + 4 * c) * 8;
#pragma unroll
      for (int j = 0; j < 8; ++j)
        wreg[c * 8 + j] = w[(size_t)(kb + j) * 64 + sn];
    }
  };
  auto writeW = [&](int s, int b) {
    float gs = 1.0f;
    if (A.gidx[s] >= 0) gs = 1.0f / (1.0f + __expf(-A.skip[A.gidx[s]]));
#pragma unroll
    for (int c = 0; c < 2; ++c) {
      int cb = wv + 4 * c;
      v8h hv, lv;
#pragma unroll
      for (int j = 0; j < 8; ++j) {
        float f = wreg[c * 8 + j] * gs;
        _Float16 h = (_Float16)f;
        hv[j] = h;
        lv[j] = (_Float16)(f - (float)h);
      }
      *(v8h*)(&sW[b][0][sn * 72 + cb * 8]) = hv;
      *(v8h*)(&sW[b][1][sn * 72 + cb * 8]) = lv;
    }
  };

  // issue W(0) global loads first so they fly under the gather
  loadW(0);

  // ---------------- Phase A: fused gather/mean ----------------
  if (A.fusedsrc >= 0) {
    const int nd = t >> 2;      // 0..63  node within block
    const int q  = t & 3;       // 16-byte column quarter
    const int node = n0 + nd;
    float a[16];
#pragma unroll
    for (int i = 0; i < 16; ++i) a[i] = 0.f;
    float dinv = 0.f;
    if (node < A.n) {
      int s = A.offs[node], e = A.offs[node + 1];
      dinv = A.invd[node];
      const unsigned char* fb = A.feat8;
      int p = s;
      for (; p + 4 <= e; p += 4) {
        int j0 = __builtin_nontemporal_load(A.csr + p);
        int j1 = __builtin_nontemporal_load(A.csr + p + 1);
        int j2 = __builtin_nontemporal_load(A.csr + p + 2);
        int j3 = __builtin_nontemporal_load(A.csr + p + 3);
        uint4 u0 = *(const uint4*)(fb + (size_t)j0 * 64 + q * 16);
        uint4 u1 = *(const uint4*)(fb + (size_t)j1 * 64 + q * 16);
        uint4 u2 = *(const uint4*)(fb + (size_t)j2 * 64 + q * 16);
        uint4 u3 = *(const uint4*)(fb + (size_t)j3 * 64 + q * 16);
        float f0[16], f1[16], f2[16], f3[16];
        dec8x16(u0, f0); dec8x16(u1, f1); dec8x16(u2, f2); dec8x16(u3, f3);
#pragma unroll
        for (int i = 0; i < 16; ++i) a[i] += (f0[i] + f1[i]) + (f2[i] + f3[i]);
      }
      for (; p < e; ++p) {
        int j = __builtin_nontemporal_load(A.csr + p);
        uint4 u = *(const uint4*)(fb + (size_t)j * 64 + q * 16);
        float f[16];
        dec8x16(u, f);
#pragma unroll
        for (int i = 0; i < 16; ++i) a[i] += f[i];
      }
    }
    v8h o0, o1;
#pragma unroll
    for (int i = 0; i < 8; ++i) {
      o0[i] = (_Float16)(a[i] * dinv);
      o1[i] = (_Float16)(a[8 + i] * dinv);
    }
    *(v8h*)(&atile[nd * 72 + q * 16]) = o0;
    *(v8h*)(&atile[nd * 72 + q * 16 + 8]) = o1;
    if (A.mout && node < A.n) {
      *(v8h*)(A.mout + (size_t)node * 64 + q * 16) = o0;
      *(v8h*)(A.mout + (size_t)node * 64 + q * 16 + 8) = o1;
    }
  }

  writeW(0, 0);
  __syncthreads();

  // ---------------- Phase B: MFMA over sources ----------------
  v4f acc[4];
#pragma unroll
  for (int ct = 0; ct < 4; ++ct) acc[ct] = (v4f){0.f, 0.f, 0.f, 0.f};

  const int arow = n0 + wv * 16 + ln;
  const bool arv = arow < A.n;
  v8h ah[2];
  auto loadA = [&](int s) {
    if (s == A.fusedsrc) {
      const _Float16* ph = atile + (wv * 16 + ln) * 72;
      ah[0] = *(const v8h*)(ph + qd * 8);
      ah[1] = *(const v8h*)(ph + 32 + qd * 8);
    } else if (arv) {
      const _Float16* ph = A.a[s] + (size_t)arow * 64;
#pragma unroll
      for (int ks = 0; ks < 2; ++ks)
        ah[ks] = *(const v8h*)(ph + ks * 32 + qd * 8);
    } else {
      v8h z;
#pragma unroll
      for (int j = 0; j < 8; ++j) z[j] = (_Float16)0.f;
      ah[0] = ah[1] = z;
    }
  };

  for (int s = 0; s < A.nsrc; ++s) {
    loadA(s);
    if (s + 1 < A.nsrc) loadW(s + 1);
    const _Float16* wh = &sW[s & 1][0][0];
    const _Float16* wl = &sW[s & 1][1][0];
#pragma unroll
    for (int ks = 0; ks < 2; ++ks) {
#pragma unroll
      for (int ct = 0; ct < 4; ++ct) {
        int wn = ct * 16 + ln;
        v8h bh = *(const v8h*)(wh + wn * 72 + ks * 32 + qd * 8);
        v8h bl = *(const v8h*)(wl + wn * 72 + ks * 32 + qd * 8);
        acc[ct] = __builtin_amdgcn_mfma_f32_16x16x32_f16(ah[ks], bh, acc[ct], 0, 0, 0);
        acc[ct] = __builtin_amdgcn_mfma_f32_16x16x32_f16(ah[ks], bl, acc[ct], 0, 0, 0);
      }
    }
    if (s + 1 < A.nsrc) writeW(s + 1, (s + 1) & 1);
    __syncthreads();
  }

  float bvals[4];
#pragma unroll
  for (int ct = 0; ct < 4; ++ct) bvals[ct] = A.bias[ct * 16 + ln];

  unsigned char* f8t = (unsigned char*)&sW[1][0][0];   // 4KB fp8 tile
  float* red = (float*)&sW[0][0][0];                    // colsum scratch

  float cs[4] = {0.f, 0.f, 0.f, 0.f};
#pragma unroll
  for (int ct = 0; ct < 4; ++ct) {
#pragma unroll
    for (int r = 0; r < 4; ++r) {
      int nb = wv * 16 + qd * 4 + r;      // row in tile
      int node = n0 + nb;                  // C/D: row=(lane>>4)*4+reg, col=lane&15
      float v = acc[ct][r] + bvals[ct];
      if (A.relu) v = fmaxf(v, 0.f);
      if (node < A.n) {
        if (A.outp) A.outp[(size_t)node * 64 + ct * 16 + ln] = (_Float16)v;
        if (A.out8) f8t[nb * 64 + ct * 16 + ln] = enc8(v);
        cs[ct] += v;
      }
    }
  }
  if (A.colsum) {
#pragma unroll
    for (int ct = 0; ct < 4; ++ct) {
      float v = cs[ct];
      v += __shfl_xor(v, 16, 64);
      v += __shfl_xor(v, 32, 64);
      if (qd == 0) red[wv * 64 + ct * 16 + ln] = v;
    }
  }
  if (A.out8 || A.colsum) __syncthreads();
  if (A.out8) {
    int row = t >> 2, ch = t & 3;
    if (n0 + row < A.n) {
      uint4 val = *(const uint4*)(f8t + row * 64 + ch * 16);
      *(uint4*)(A.out8 + (size_t)(n0 + row) * 64 + ch * 16) = val;
    }
  }
  if (A.colsum && t < 64) {
    float ssum = red[t] + red[64 + t] + red[128 + t] + red[192 + t];
    atomicAdd(&A.colsum[t], ssum);
  }
}

// ============== fused pre-MLP: x = (relu(nf@W1+b1))@W2 + b2 ===================
// Stage1 (K=128, fp32 A) -> LDS fp16 tile -> Stage2 -> x fp16 + x fp8 + colsum.
__global__ __launch_bounds__(256) void k_pre(
    const float* __restrict__ nf,
    const float* __restrict__ w1, const float* __restrict__ b1,
    const float* __restrict__ w2, const float* __restrict__ b2,
    _Float16* __restrict__ xout, unsigned char* __restrict__ x8,
    float* __restrict__ colsum, int n) {
  __shared__ _Float16 sW[2][2][64 * 72];
  __shared__ _Float16 atile[64 * 72];
  const int t    = threadIdx.x;
  const int lane = t & 63;
  const int wv   = t >> 6;
  const int qd   = lane >> 4;
  const int ln   = lane & 15;
  const int n0   = blockIdx.x * 64;
  const int sn   = t & 63;

  float wreg[16];
  auto loadW = [&](const float* w) {
#pragma unroll
    for (int c = 0; c < 2; ++c) {
      int kb = (wv + 4 * c) * 8;
#pragma unroll
      for (int j = 0; j < 8; ++j)
        wreg[c * 8 + j] = w[(size_t)(kb + j) * 64 + sn];
    }
  };
  auto writeW = [&](int b) {
#pragma unroll
    for (int c = 0; c < 2; ++c) {
      int cb = wv + 4 * c;
      v8h hv, lv;
#pragma unroll
      for (int j = 0; j < 8; ++j) {
        float f = wreg[c * 8 + j];
        _Float16 h = (_Float16)f;
        hv[j] = h;
        lv[j] = (_Float16)(f - (float)h);
      }
      *(v8h*)(&sW[b][0][sn * 72 + cb * 8]) = hv;
      *(v8h*)(&sW[b][1][sn * 72 + cb * 8]) = lv;
    }
  };

  const int arow = n0 + wv * 16 + ln;
  const bool arv = arow < n;
  v4f acc[4];
#pragma unroll
  for (int ct = 0; ct < 4; ++ct) acc[ct] = (v4f){0.f, 0.f, 0.f, 0.f};
  v8h ah[2];

  auto loadAf32 = [&](const float* base) {
#pragma unroll
    for (int ks = 0; ks < 2; ++ks) {
      v8h hv;
      if (arv) {
        const float* p = base + (size_t)arow * 128 + ks * 32 + qd * 8;
        float4 u0 = *(const float4*)(p);
        float4 u1 = *(const float4*)(p + 4);
        hv[0] = (_Float16)u0.x; hv[1] = (_Float16)u0.y;
        hv[2] = (_Float16)u0.z; hv[3] = (_Float16)u0.w;
        hv[4] = (_Float16)u1.x; hv[5] = (_Float16)u1.y;
        hv[6] = (_Float16)u1.z; hv[7] = (_Float16)u1.w;
      } else {
#pragma unroll
        for (int j = 0; j < 8; ++j) hv[j] = (_Float16)0.f;
      }
      ah[ks] = hv;
    }
  };
  auto domfma = [&](int b) {
    const _Float16* wh = &sW[b][0][0];
    const _Float16* wl = &sW[b][1][0];
#pragma unroll
    for (int ks = 0; ks < 2; ++ks) {
#pragma unroll
      for (int ct = 0; ct < 4; ++ct) {
        int wn = ct * 16 + ln;
        v8h bh = *(const v8h*)(wh + wn * 72 + ks * 32 + qd * 8);
        v8h bl = *(const v8h*)(wl + wn * 72 + ks * 32 + qd * 8);
        acc[ct] = __builtin_amdgcn_mfma_f32_16x16x32_f16(ah[ks], bh, acc[ct], 0, 0, 0);
        acc[ct] = __builtin_amdgcn_mfma_f32_16x16x32_f16(ah[ks], bl, acc[ct], 0, 0, 0);
      }
    }
  };

  // stage 1: t0 = relu(nf@W1 + b1), K=128 as two 64-col sources
  loadW(w1);
  writeW(0);
  __syncthreads();
  loadAf32(nf);
  loadW(w1 + 64 * 64);
  domfma(0);
  writeW(1);
  __syncthreads();
  loadAf32(nf + 64);
  loadW(w2);
  domfma(1);
  writeW(0);          // W2 into buf0 (buf0 reads completed before last barrier)

  float b1v[4];
#pragma unroll
  for (int ct = 0; ct < 4; ++ct) b1v[ct] = b1[ct * 16 + ln];
#pragma unroll
  for (int ct = 0; ct < 4; ++ct) {
#pragma unroll
    for (int r = 0; r < 4; ++r) {
      int nb = wv * 16 + qd * 4 + r;
      float v = fmaxf(acc[ct][r] + b1v[ct], 0.f);
      atile[nb * 72 + ct * 16 + ln] = (_Float16)v;
    }
  }
#pragma unroll
  for (int ct = 0; ct < 4; ++ct) acc[ct] = (v4f){0.f, 0.f, 0.f, 0.f};
  __syncthreads();

  // stage 2: x = t0 @ W2 + b2
  const int trow = wv * 16 + ln;
#pragma unroll
  for (int ks = 0; ks < 2; ++ks)
    ah[ks] = *(const v8h*)(atile + trow * 72 + ks * 32 + qd * 8);
  domfma(0);

  float b2v[4];
#pragma unroll
  for (int ct = 0; ct < 4; ++ct) b2v[ct] = b2[ct * 16 + ln];

  unsigned char* f8t = (unsigned char*)&sW[1][0][0];
  float* red = (float*)&sW[0][0][0];
  float cs[4] = {0.f, 0.f, 0.f, 0.f};
  __syncthreads();   // atile reads done; sW reuse safe
#pragma unroll
  for (int ct = 0; ct < 4; ++ct) {
#pragma unroll
    for (int r = 0; r < 4; ++r) {
      int nb = wv * 16 + qd * 4 + r;
      int node = n0 + nb;
      float v = acc[ct][r] + b2v[ct];
      if (node < n) {
        xout[(size_t)node * 64 + ct * 16 + ln] = (_Float16)v;
        f8t[nb * 64 + ct * 16 + ln] = enc8(v);
        cs[ct] += v;
      }
    }
  }
#pragma unroll
  for (int ct = 0; ct < 4; ++ct) {
    float v = cs[ct];
    v += __shfl_xor(v, 16, 64);
    v += __shfl_xor(v, 32, 64);
    if (qd == 0) red[wv * 64 + ct * 16 + ln] = v;
  }
  __syncthreads();
  {
    int row = t >> 2, ch = t & 3;
    if (n0 + row < n) {
      uint4 val = *(const uint4*)(f8t + row * 64 + ch * 16);
      *(uint4*)(x8 + (size_t)(n0 + row) * 64 + ch * 16) = val;
    }
  }
  if (t < 64) {
    float ssum = red[t] + red[64 + t] + red[128 + t] + red[192 + t];
    atomicAdd(&colsum[t], ssum);
  }
}

// ---------------- tiny post-MLP (single block) ----------------
__global__ __launch_bounds__(256) void k_post(const float* __restrict__ s,
                                              const float* __restrict__ w1, const float* __restrict__ b1,
                                              const float* __restrict__ w2, const float* __restrict__ b2,
                                              const float* __restrict__ w3, const float* __restrict__ b3,
                                              const float* __restrict__ w4, const float* __restrict__ b4,
                                              float* __restrict__ outp) {
  __shared__ float sh[256], h1[64], h2[64], h3[256];
  int t = threadIdx.x;
  sh[t] = s[t];
  __syncthreads();
  if (t < 64) {
    float a = b1[t];
    for (int k = 0; k < 256; ++k) a += sh[k] * w1[k * 64 + t];
    h1[t] = (a >= 0.f) ? a : 0.1f * a;   // leaky_relu 0.1
  }
  __syncthreads();
  if (t < 64) {
    float a = b2[t];
    for (int k = 0; k < 64; ++k) a += h1[k] * w2[k * 64 + t];
    h2[t] = fmaxf(a, 0.f);
  }
  __syncthreads();
  {
    float a = b3[t];
    for (int k = 0; k < 64; ++k) a += h2[k] * w3[k * 256 + t];
    h3[t] = fmaxf(a, 0.f);
  }
  __syncthreads();
  if (t < 64) {
    float a = b4[t];
    for (int k = 0; k < 256; ++k) a += h3[k] * w4[k * 64 + t];
    outp[t] = a;
  }
}

extern "C" void kernel_launch(void* const* d_in, const int* in_sizes, int n_in,
                              void* d_out, int out_size, void* d_ws, size_t ws_size,
                              hipStream_t stream) {
  const float* nf     = (const float*)d_in[0];
  const int*   ei     = (const int*)d_in[1];
  const float* pre_w1 = (const float*)d_in[2];
  const float* pre_b1 = (const float*)d_in[3];
  const float* pre_w2 = (const float*)d_in[4];
  const float* pre_b2 = (const float*)d_in[5];
  const float* skip   = (const float*)d_in[6];
  const float* wl0 = (const float*)d_in[7],  *bl0 = (const float*)d_in[8],  *wr0 = (const float*)d_in[9];
  const float* wl1 = (const float*)d_in[10], *bl1 = (const float*)d_in[11], *wr1 = (const float*)d_in[12];
  const float* wl2 = (const float*)d_in[13], *bl2 = (const float*)d_in[14], *wr2 = (const float*)d_in[15];
  const float* pw1 = (const float*)d_in[16], *pb1 = (const float*)d_in[17];
  const float* pw2 = (const float*)d_in[18], *pb2 = (const float*)d_in[19];
  const float* pw3 = (const float*)d_in[20], *pb3 = (const float*)d_in[21];
  const float* pw4 = (const float*)d_in[22], *pb4 = (const float*)d_in[23];
  float* out = (float*)d_out;

  const int N = NN, E = NE;

  // workspace carve-up
  char* ws = (char*)d_ws;
  size_t pos = 0;
  auto alloc = [&](size_t bytes) {
    char* p = ws + pos;
    pos += (bytes + 255) & ~(size_t)255;
    return (void*)p;
  };
  int*      gbcnt = (int*)alloc((size_t)NB * 4);
  int*      boff  = (int*)alloc((size_t)(NB + 1) * 4);
  int*      gcur  = (int*)alloc((size_t)NB * 4);
  unsigned* ebuf  = (unsigned*)alloc((size_t)E * 4);
  int*      offs  = (int*)alloc((size_t)(N + 1) * 4);
  float*    invd  = (float*)alloc((size_t)N * 4);
  int*      csr   = (int*)alloc((size_t)E * 4);
  const size_t PB = (size_t)N * 64 * 2;   // fp16 rows, bytes
  _Float16* x  = (_Float16*)alloc(PB);
  _Float16* h0 = (_Float16*)alloc(PB);
  _Float16* h1 = (_Float16*)alloc(PB);
  _Float16* m0 = (_Float16*)alloc(PB);
  _Float16* m1 = (_Float16*)alloc(PB);
  unsigned char* f8 = (unsigned char*)alloc((size_t)N * 64);  // rotating gather table
  float* sv = (float*)alloc(256 * 4);

  hipMemsetAsync(gbcnt, 0, (size_t)NB * 4, stream);

  const int* e_src = ei;
  const int* e_dst = ei + E;
  const int EGRID = (E + 4095) / 4096;   // 196
  k_bhist<<<EGRID, 256, 0, stream>>>(e_dst, gbcnt);
  k_bscan<<<1, 256, 0, stream>>>(gbcnt, boff, gcur, offs, sv);
  k_bscatter<<<EGRID, 256, 0, stream>>>(e_src, e_dst, gcur, ebuf);
  k_bbuild<<<NB, 256, 0, stream>>>(ebuf, boff, offs, invd, csr);

  const int LGRID = (N + 63) / 64;   // 782
  auto lin = [&](int nsrc, int fusedsrc, _Float16* mout,
                 const _Float16* a0, const float* w0, int g0,
                 const _Float16* a1, const float* w1_, int g1,
                 const _Float16* a2, const float* w2_, int g2,
                 const _Float16* a3, const float* w3_, int g3,
                 const _Float16* a4, const float* w4_, int g4,
                 const _Float16* a5, const float* w5_, int g5,
                 const float* bias, _Float16* op, unsigned char* o8,
                 float* colsum, int relu) {
    LinArgs A;
    A.a[0] = a0; A.a[1] = a1; A.a[2] = a2; A.a[3] = a3; A.a[4] = a4; A.a[5] = a5;
    A.w[0] = w0; A.w[1] = w1_; A.w[2] = w2_; A.w[3] = w3_; A.w[4] = w4_; A.w[5] = w5_;
    A.gidx[0] = g0; A.gidx[1] = g1; A.gidx[2] = g2; A.gidx[3] = g3; A.gidx[4] = g4; A.gidx[5] = g5;
    A.nsrc = nsrc; A.fusedsrc = fusedsrc;
    A.feat8 = f8; A.offs = offs; A.csr = csr; A.invd = invd;
    A.mout = mout;
    A.bias = bias; A.skip = skip;
    A.outp = op; A.out8 = o8; A.colsum = colsum;
    A.n = N; A.relu = relu;
    k_linear<<<LGRID, 256, 0, stream>>>(A);
  };

  // fused pre-MLP: x (fp16 + fp8) + colsum sv[0:64]
  k_pre<<<LGRID, 256, 0, stream>>>(nf, pre_w1, pre_b1, pre_w2, pre_b2,
                                   x, f8, sv, N);

  // layer 0: fused agg(x_fp8)->m0 ; h0 = relu(m0@wl0 + x@wr0 + bl0)
  lin(2, 0, m0,
      nullptr, wl0, 0, x, wr0, 0,
      nullptr, nullptr, -1, nullptr, nullptr, -1,
      nullptr, nullptr, -1, nullptr, nullptr, -1,
      bl0, h0, f8, sv + 64, 1);

  // layer 1: fused agg(h0_fp8)->m1 (gates skip[1][0]=idx3, skip[1][1]=idx4)
  lin(4, 1, m1,
      m0, wl1, 3, nullptr, wl1 + 64 * 64, 4,
      x, wr1, 3, h0, wr1 + 64 * 64, 4,
      nullptr, nullptr, -1, nullptr, nullptr, -1,
      bl1, h1, f8, sv + 128, 1);

  // layer 2: fused agg(h1_fp8)->m2 (discarded); colsum only (gates idx 6,7,8)
  lin(6, 2, nullptr,
      m0, wl2, 6, m1, wl2 + 64 * 64, 7, nullptr, wl2 + 128 * 64, 8,
      x, wr2, 6, h0, wr2 + 64 * 64, 7, h1, wr2 + 128 * 64, 8,
      bl2, nullptr, nullptr, sv + 192, 1);

  // post-MLP on the fused column sums
  k_post<<<1, 256, 0, stream>>>(sv, pw1, pb1, pw2, pb2, pw3, pb3, pw4, pb4, out);
}